// Round 17
// baseline (89.431 us; speedup 1.0000x reference)
//
#include <hip/hip_runtime.h>

// Problem constants (fixed by setup_inputs)
#define B_   4
#define C_   256
#define H_   96
#define W_   128
#define F_   9
#define G_   4
#define CG   64            // channels per group
#define NC8  8             // channel OCTETS per group
#define NO   81            // offsets
#define HW_  (H_ * W_)

// One dy per pass (9 passes). Block = 4 out-rows x 128 cols, 2 px/thread.
#define OROWS 4
#define TCOLS 144                 // 128 + 16 halo cols
#define PSTR  73                  // parity-plane stride (73 mod 8 = 1 -> 8 lanes/quad)
#define NENT  (OROWS * 2 * PSTR)  // 584 16B-entries per buffer
#define NPIX  (OROWS * TCOLS)     // 576 halo pixels to stage
#define PNK   3                   // staging chunks 256+256+64
#define NW    (NC8 * F_)          // 72 weight entries in LDS

typedef _Float16 half2v __attribute__((ext_vector_type(2)));
typedef unsigned u32x4 __attribute__((ext_vector_type(4)));

__device__ __forceinline__ half2v u2h(unsigned u) {
    half2v h; __builtin_memcpy(&h, &u, 4); return h;
}
__device__ __forceinline__ unsigned h2u(half2v h) {
    unsigned u; __builtin_memcpy(&u, &h, 4); return u;
}
__device__ __forceinline__ half2v pkrtz(float a, float b) {
    auto r = __builtin_amdgcn_cvt_pkrtz(a, b);
    half2v h; __builtin_memcpy(&h, &r, 4); return h;
}
__device__ __forceinline__ unsigned pkrtz_u(float a, float b) {
    auto r = __builtin_amdgcn_cvt_pkrtz(a, b);
    unsigned u; __builtin_memcpy(&u, &r, 4); return u;
}

#if __has_builtin(__builtin_amdgcn_fdot2)
#define FDOT2(a, b, c) __builtin_amdgcn_fdot2((a), (b), (c), false)
#else
__device__ __forceinline__ float fdot2_fb(half2v a, half2v b, float c) {
    return c + (float)a[0] * (float)b[0] + (float)a[1] * (float)b[1];
}
#define FDOT2(a, b, c) fdot2_fb((a), (b), (c))
#endif

// Pack weights [C,9,9] f32 -> [g][c8][o] as 8-channel (4x f16x2) in d_ws
__global__ void pack_weights_kernel(const float* __restrict__ w,
                                    u32x4* __restrict__ wp) {
    int i = blockIdx.x * blockDim.x + threadIdx.x;
    if (i >= G_ * NC8 * NO) return;
    int o  = i % NO;
    int c8 = (i / NO) % NC8;
    int g  = i / (NO * NC8);
    const float* base = w + (size_t)(g * CG + 8 * c8) * NO + o;
    u32x4 r;
    r.x = pkrtz_u(base[0 * NO], base[1 * NO]);
    r.y = pkrtz_u(base[2 * NO], base[3 * NO]);
    r.z = pkrtz_u(base[4 * NO], base[5 * NO]);
    r.w = pkrtz_u(base[6 * NO], base[7 * NO]);
    wp[i] = r;
}

template <bool PACKED>
__global__ __launch_bounds__(256)
void wcorr_kernel(const float* __restrict__ in1, const float* __restrict__ in2,
                  const u32x4* __restrict__ wp, const float* __restrict__ wraw,
                  float* __restrict__ out) {
    // tap entry = (row*2 + parity)*PSTR + col2
    __shared__ u32x4 tile[2][NENT];   // 18,688 B
    __shared__ u32x4 wlds[NW];        // 1,152 B — this block's (g, dy) weight slice

    // grid = 8 XCD x 48 tuples x 9 dy = 3456; dy innermost per tuple -> the 9
    // blocks sharing in1 rows run consecutively on the SAME XCD (R9/R13-proven).
    int bid   = blockIdx.x;
    int xcd   = bid & 7;
    int slot  = bid >> 3;               // 0..431
    int tuple = slot / 9;
    int dy    = slot - tuple * 9;       // 0..8
    int T     = tuple * 8 + xcd;        // 0..383
    int pair  = T & 15;                 // b*4+g
    int hblk  = T >> 4;                 // 0..23
    int b = pair >> 2, g = pair & 3;
    int h0 = hblk * OROWS;

    int t = threadIdx.x;
    int r = t >> 6;                     // 0..3 out row (wave-uniform)
    int i = t & 63;
    int j = i >> 1;                     // 0..31
    int p = i & 1;                      // parity
    const int c0 = 4 * j + p;           // px0 col; px1 = c0 + 2

    const float* in1g = in1 + (size_t)(b * C_ + g * CG) * HW_;
    const float* in2g = in2 + (size_t)(b * C_ + g * CG) * HW_;

    // ---- stage weight slice (8 c8 x 9 dx) into LDS once ----
    if (t < NW) {
        int c8s = t / F_;
        int dxs = t - F_ * c8s;
        if (PACKED) {
            wlds[t] = wp[((size_t)(g * NC8 + c8s)) * NO + dy * F_ + dxs];
        } else {
            const float* base = wraw + (size_t)(g * CG + 8 * c8s) * NO + dy * F_ + dxs;
            u32x4 e;
            e.x = pkrtz_u(base[0 * NO], base[1 * NO]);
            e.y = pkrtz_u(base[2 * NO], base[3 * NO]);
            e.z = pkrtz_u(base[4 * NO], base[5 * NO]);
            e.w = pkrtz_u(base[6 * NO], base[7 * NO]);
            wlds[t] = e;
        }
    }

    // ---- staging geometry (c8-invariant): clamp + mask, branchless ----
    const int gr0 = h0 + 2 * dy - 8;
    int po[PNK]; unsigned msk[PNK]; int lix[PNK];
#pragma unroll
    for (int k = 0; k < PNK; ++k) {
        int pidx = k * 256 + t;
        int srow = pidx / TCOLS;
        int col  = pidx - srow * TCOLS;
        int gr = gr0 + srow, gc = col - 8;
        bool inb = (pidx < NPIX) && gr >= 0 && gr < H_ && gc >= 0 && gc < W_;
        int off = gr * W_ + gc;
        off = off < 0 ? 0 : (off > HW_ - 1 ? HW_ - 1 : off);
        po[k]  = off;
        float m = inb ? 1.f : 0.f;
        msk[k] = pkrtz_u(m, m);
        lix[k] = (srow * 2 + (col & 1)) * PSTR + (col >> 1);
    }

    float acc0[F_], acc1[F_];
#pragma unroll
    for (int dx = 0; dx < F_; ++dx) { acc0[dx] = 0.f; acc1[dx] = 0.f; }

    // staged in2 values for ONE tile, live across a full compute phase
    float sv[PNK][8];

    auto LOADS = [&](int c8n) {
        const float* chb = in2g + (size_t)(8 * c8n) * HW_;
#pragma unroll
        for (int k = 0; k < PNK; ++k) {
            if (k < PNK - 1 || t < NPIX - (PNK - 1) * 256) {
                const float* q = chb + po[k];
#pragma unroll
                for (int c = 0; c < 8; ++c) sv[k][c] = q[(size_t)c * HW_];
            }
        }
    };
    auto WRITE = [&](u32x4* dst) {
#pragma unroll
        for (int k = 0; k < PNK; ++k) {
            if (k < PNK - 1 || t < NPIX - (PNK - 1) * 256) {
                half2v m = u2h(msk[k]);
                u32x4 e;
                e.x = h2u(u2h(pkrtz_u(sv[k][0], sv[k][1])) * m);
                e.y = h2u(u2h(pkrtz_u(sv[k][2], sv[k][3])) * m);
                e.z = h2u(u2h(pkrtz_u(sv[k][4], sv[k][5])) * m);
                e.w = h2u(u2h(pkrtz_u(sv[k][6], sv[k][7])) * m);
                dst[lix[k]] = e;    // ds_write_b128 (8 lanes/quad uniform)
            }
        }
    };

    // ---- prologue: tile 0 staged; tile 1 loads in flight; in1 for c8=0 ----
    LOADS(0);
    WRITE(tile[0]);
    LOADS(1);

    const int in1off = (h0 + r) * W_ + c0;
    float a[16];    // a[0..7] = px0 channels, a[8..15] = px1 channels
    {
        const float* ib = in1g + in1off;
#pragma unroll
        for (int c = 0; c < 8; ++c) {
            a[c]     = ib[(size_t)c * HW_];
            a[8 + c] = ib[(size_t)c * HW_ + 2];
        }
    }

    // per-lane window base: tap m -> entry wb + m (compile-time m)
    const int wb = (r * 2 + p) * PSTR + 2 * j;

    for (int c8 = 0; c8 < NC8; ++c8) {
        __syncthreads();   // tile[c8&1] readable (+ wlds on 1st iter)

        if (c8 + 1 < NC8) WRITE(tile[(c8 + 1) & 1]);   // loads 1 iter old
        if (c8 + 2 < NC8) LOADS(c8 + 2);               // wait lands next WRITE

        // pack current in1 (2 px), then prefetch next octet
        half2v ha0 = pkrtz(a[0], a[1]),   ha1 = pkrtz(a[2], a[3]);
        half2v ha2 = pkrtz(a[4], a[5]),   ha3 = pkrtz(a[6], a[7]);
        half2v hb0 = pkrtz(a[8], a[9]),   hb1 = pkrtz(a[10], a[11]);
        half2v hb2 = pkrtz(a[12], a[13]), hb3 = pkrtz(a[14], a[15]);
        if (c8 + 1 < NC8) {
            const float* ib = in1g + (size_t)(8 * (c8 + 1)) * HW_ + in1off;
#pragma unroll
            for (int c = 0; c < 8; ++c) {
                a[c]     = ib[(size_t)c * HW_];
                a[8 + c] = ib[(size_t)c * HW_ + 2];
            }
        }

        const u32x4* lt = tile[c8 & 1] + wb;
        const u32x4* wl = wlds + c8 * F_;    // broadcast reads (uniform addr)

        // one tap read per window entry m; weight for dx=m read once and
        // CARRIED in a register for px1's use at m+1 (no dual fetch)
        u32x4 wv = {0u, 0u, 0u, 0u}, wprev;
#pragma unroll
        for (int m = 0; m < 10; ++m) {
            u32x4 uv = lt[m];                // ds_read_b128 offset:16*m
            wprev = wv;
            if (m <= 8) {
                wv = wl[m];                  // ds_read_b128 broadcast
                float s = acc0[m];
                s = FDOT2(u2h(wv.x) * ha0, u2h(uv.x), s);
                s = FDOT2(u2h(wv.y) * ha1, u2h(uv.y), s);
                s = FDOT2(u2h(wv.z) * ha2, u2h(uv.z), s);
                s = FDOT2(u2h(wv.w) * ha3, u2h(uv.w), s);
                acc0[m] = s;
            }
            if (m >= 1) {
                float s = acc1[m - 1];
                s = FDOT2(u2h(wprev.x) * hb0, u2h(uv.x), s);
                s = FDOT2(u2h(wprev.y) * hb1, u2h(uv.y), s);
                s = FDOT2(u2h(wprev.z) * hb2, u2h(uv.z), s);
                s = FDOT2(u2h(wprev.w) * hb3, u2h(uv.w), s);
                acc1[m - 1] = s;
            }
        }
    }

    // out[b][g*81 + dy*9 + dx][h0+r][c0], [c0+2]
    size_t obase = (((size_t)(pair * NO + dy * F_)) * H_ + (h0 + r)) * W_ + c0;
#pragma unroll
    for (int dx = 0; dx < F_; ++dx) {
        out[obase + (size_t)dx * HW_]     = acc0[dx];
        out[obase + (size_t)dx * HW_ + 2] = acc1[dx];
    }
}

extern "C" void kernel_launch(void* const* d_in, const int* in_sizes, int n_in,
                              void* d_out, int out_size, void* d_ws, size_t ws_size,
                              hipStream_t stream) {
    const float* in1  = (const float*)d_in[0];
    const float* in2  = (const float*)d_in[1];
    const float* wraw = (const float*)d_in[2];
    float* out = (float*)d_out;

    const size_t wp_bytes = (size_t)G_ * NC8 * NO * 16;  // 41,472 B
    const int nblocks = 8 * 48 * F_;                     // 3456

    if (ws_size >= wp_bytes) {
        u32x4* wp = (u32x4*)d_ws;
        int n = G_ * NC8 * NO;
        pack_weights_kernel<<<(n + 255) / 256, 256, 0, stream>>>(wraw, wp);
        wcorr_kernel<true><<<nblocks, 256, 0, stream>>>(in1, in2, wp, wraw, out);
    } else {
        wcorr_kernel<false><<<nblocks, 256, 0, stream>>>(in1, in2, nullptr, wraw, out);
    }
}

// Round 18
// 77.440 us; speedup vs baseline: 1.1548x; 1.1548x over previous
//
#include <hip/hip_runtime.h>

// Problem constants (fixed by setup_inputs)
#define B_   4
#define C_   256
#define H_   96
#define W_   128
#define F_   9
#define G_   4
#define CG   64            // channels per group
#define NC8  8             // channel OCTETS per group
#define NO   81            // offsets
#define HW_  (H_ * W_)

// Block: 4 output rows x 64 cols (half width); 3 dy per pass (R11 anchor)
#define NDY   3
#define TROWS 8                  // tap rows: r + 2*dyp, r=0..3, dyp=0..2 -> 0..7
#define TCOLS 80                 // 64 + 16 halo cols
#define PTE   (TROWS * TCOLS)    // 960? no: 8*80 = 640 entries (16B: 8ch f16)
#define PNK   3                  // staging chunks 256+256+128

typedef _Float16 half2v __attribute__((ext_vector_type(2)));
typedef unsigned u32x4 __attribute__((ext_vector_type(4)));

__device__ __forceinline__ half2v u2h(unsigned u) {
    half2v h; __builtin_memcpy(&h, &u, 4); return h;
}
__device__ __forceinline__ unsigned h2u(half2v h) {
    unsigned u; __builtin_memcpy(&u, &h, 4); return u;
}
__device__ __forceinline__ half2v pkrtz(float a, float b) {
    auto r = __builtin_amdgcn_cvt_pkrtz(a, b);
    half2v h; __builtin_memcpy(&h, &r, 4); return h;
}
__device__ __forceinline__ unsigned pkrtz_u(float a, float b) {
    auto r = __builtin_amdgcn_cvt_pkrtz(a, b);
    unsigned u; __builtin_memcpy(&u, &r, 4); return u;
}

#if __has_builtin(__builtin_amdgcn_fdot2)
#define FDOT2(a, b, c) __builtin_amdgcn_fdot2((a), (b), (c), false)
#else
__device__ __forceinline__ float fdot2_fb(half2v a, half2v b, float c) {
    return c + (float)a[0] * (float)b[0] + (float)a[1] * (float)b[1];
}
#define FDOT2(a, b, c) fdot2_fb((a), (b), (c))
#endif

// Pack weights [C,9,9] f32 -> [g][c8][o] as 8-channel (4x f16x2) in d_ws
__global__ void pack_weights_kernel(const float* __restrict__ w,
                                    u32x4* __restrict__ wp) {
    int i = blockIdx.x * blockDim.x + threadIdx.x;
    if (i >= G_ * NC8 * NO) return;
    int o  = i % NO;
    int c8 = (i / NO) % NC8;
    int g  = i / (NO * NC8);
    const float* base = w + (size_t)(g * CG + 8 * c8) * NO + o;
    u32x4 r;
    r.x = pkrtz_u(base[0 * NO], base[1 * NO]);
    r.y = pkrtz_u(base[2 * NO], base[3 * NO]);
    r.z = pkrtz_u(base[4 * NO], base[5 * NO]);
    r.w = pkrtz_u(base[6 * NO], base[7 * NO]);
    wp[i] = r;
}

template <bool PACKED>
__global__ __launch_bounds__(256)
void wcorr_kernel(const float* __restrict__ in1, const float* __restrict__ in2,
                  const u32x4* __restrict__ wp, const float* __restrict__ wraw,
                  float* __restrict__ out) {
    __shared__ u32x4 tile[2][PTE];   // 20,480 B

    // grid = 2304: 16 pairs x {3 pass x 24 hblk x 2 half}
    // XCD-aware: (b,g) pair constant per XCD run -> in2 plane stays in XCD L2
    int bid  = blockIdx.x;
    int xcd  = bid & 7;
    int slot = bid >> 3;                 // 0..287
    int pair = xcd + 8 * (slot / 144);   // 0..15  == b*4+g
    int rem  = slot % 144;
    int pass = rem / 48;                 // 0..2  (dy block)
    int sub  = rem % 48;
    int hblk = sub >> 1;                 // 0..23
    int half = sub & 1;                  // col half
    int b = pair >> 2, g = pair & 3;
    int h0 = hblk * 4;
    int w0 = half * 64;

    int t = threadIdx.x;
    int r = t >> 6;                 // 0..3 output row (uniform per wave)
    int x = t & 63;                 // 0..63 output col within half

    const float* in1g = in1 + (size_t)(b * C_ + g * CG) * HW_;
    const float* in2g = in2 + (size_t)(b * C_ + g * CG) * HW_;

    // ---- staging geometry (c8-invariant): clamp + mask, branchless ----
    const int gr0 = h0 - 8 + 6 * pass;
    const int gc0 = w0 - 8;
    int po[PNK]; unsigned msk[PNK];
#pragma unroll
    for (int k = 0; k < PNK; ++k) {
        int pidx = k * 256 + t;
        int row  = pidx / TCOLS;
        int col  = pidx - row * TCOLS;
        int gr = gr0 + row, gc = gc0 + col;
        bool inb = (pidx < PTE) && gr >= 0 && gr < H_ && gc >= 0 && gc < W_;
        int off = gr * W_ + gc;
        off = off < 0 ? 0 : (off > HW_ - 1 ? HW_ - 1 : off);
        po[k]  = off;
        float m = inb ? 1.f : 0.f;
        msk[k] = pkrtz_u(m, m);
    }

    float acc[NDY * F_];
#pragma unroll
    for (int o = 0; o < NDY * F_; ++o) acc[o] = 0.f;

    // staged in2 values for ONE tile (8 ch x PNK chunks), live across compute
    float sv[PNK][8];

    auto LOADS = [&](int c8n) {
        const float* chb = in2g + (size_t)(8 * c8n) * HW_;
#pragma unroll
        for (int k = 0; k < PNK; ++k) {
            const float* q = chb + po[k];
#pragma unroll
            for (int j = 0; j < 8; ++j) sv[k][j] = q[(size_t)j * HW_];
        }
    };
    auto WRITE = [&](u32x4* dst) {
#pragma unroll
        for (int k = 0; k < PNK; ++k) {
            if (k < PNK - 1 || t < PTE - (PNK - 1) * 256) {
                half2v m = u2h(msk[k]);
                u32x4 e;
                e.x = h2u(u2h(pkrtz_u(sv[k][0], sv[k][1])) * m);
                e.y = h2u(u2h(pkrtz_u(sv[k][2], sv[k][3])) * m);
                e.z = h2u(u2h(pkrtz_u(sv[k][4], sv[k][5])) * m);
                e.w = h2u(u2h(pkrtz_u(sv[k][6], sv[k][7])) * m);
                dst[k * 256 + t] = e;    // ds_write_b128, contiguous
            }
        }
    };

    // ---- prologue: tile 0 staged; tile 1 loads in flight ----
    LOADS(0);
    WRITE(tile[0]);
    LOADS(1);

    const int in1off = (h0 + r) * W_ + (w0 + x);
    float a[8];
#pragma unroll
    for (int j = 0; j < 8; ++j) a[j] = in1g[in1off + (size_t)j * HW_];

    for (int c8 = 0; c8 < NC8; ++c8) {
        __syncthreads();   // tile[c8&1] readable; tile[(c8+1)&1] writable

        // pack current in1 first (VALU, frees a[]), then issue next in1 octet
        // BEFORE the LDS write phase so its latency hides under WRITE+inner
        half2v ha0 = pkrtz(a[0], a[1]), ha1 = pkrtz(a[2], a[3]);
        half2v ha2 = pkrtz(a[4], a[5]), ha3 = pkrtz(a[6], a[7]);
        if (c8 + 1 < NC8) {
            const float* pp = in1g + (size_t)(8 * (c8 + 1)) * HW_ + in1off;
#pragma unroll
            for (int j = 0; j < 8; ++j) a[j] = pp[(size_t)j * HW_];
        }

        // write tile c8+1 (loads issued one FULL iteration ago -> vmcnt covered)
        if (c8 + 1 < NC8) WRITE(tile[(c8 + 1) & 1]);
        // issue loads for tile c8+2 (wait lands in NEXT iteration's WRITE)
        if (c8 + 2 < NC8) LOADS(c8 + 2);

        const u32x4* lt = tile[c8 & 1];
        const u32x4* wrow = PACKED ? (wp + ((size_t)g * NC8 + c8) * NO + pass * NDY * F_) : nullptr;
        const float* wr = wraw + (size_t)(g * CG + 8 * c8) * NO + pass * NDY * F_;

        // T5: bias CU scheduler toward compute-phase waves (blocks are
        // unsynchronized -> resident blocks sit at different phases)
        __builtin_amdgcn_s_setprio(1);
#pragma unroll
        for (int dyp = 0; dyp < NDY; ++dyp) {
            const u32x4* rowp = lt + (r + 2 * dyp) * TCOLS + x;
#pragma unroll
            for (int dx = 0; dx < F_; ++dx) {
                const int oo = dyp * F_ + dx;
                u32x4 uv = rowp[2 * dx];            // ds_read_b128, imm offset
                half2v w0h, w1h, w2h, w3h;
                if (PACKED) {
                    u32x4 wv = wrow[oo];            // block-uniform -> s_load x4
                    w0h = u2h(wv.x); w1h = u2h(wv.y);
                    w2h = u2h(wv.z); w3h = u2h(wv.w);
                } else {
                    w0h = pkrtz(wr[oo + 0 * NO], wr[oo + 1 * NO]);
                    w1h = pkrtz(wr[oo + 2 * NO], wr[oo + 3 * NO]);
                    w2h = pkrtz(wr[oo + 4 * NO], wr[oo + 5 * NO]);
                    w3h = pkrtz(wr[oo + 6 * NO], wr[oo + 7 * NO]);
                }
                float s = acc[oo];
                s = FDOT2(w0h * ha0, u2h(uv.x), s);
                s = FDOT2(w1h * ha1, u2h(uv.y), s);
                s = FDOT2(w2h * ha2, u2h(uv.z), s);
                s = FDOT2(w3h * ha3, u2h(uv.w), s);
                acc[oo] = s;
            }
        }
        __builtin_amdgcn_s_setprio(0);
    }

    // out[b][g*81 + pass*27 + oo][h0+r][w0+x]
    size_t obase = (((size_t)pair * NO + pass * NDY * F_) * H_ + (h0 + r)) * W_ + (w0 + x);
#pragma unroll
    for (int oo = 0; oo < NDY * F_; ++oo)
        out[obase + (size_t)oo * HW_] = acc[oo];
}

extern "C" void kernel_launch(void* const* d_in, const int* in_sizes, int n_in,
                              void* d_out, int out_size, void* d_ws, size_t ws_size,
                              hipStream_t stream) {
    const float* in1  = (const float*)d_in[0];
    const float* in2  = (const float*)d_in[1];
    const float* wraw = (const float*)d_in[2];
    float* out = (float*)d_out;

    const size_t wp_bytes = (size_t)G_ * NC8 * NO * 16;  // 41,472 B
    const int nblocks = 16 * 3 * 24 * 2;                 // 2304

    if (ws_size >= wp_bytes) {
        u32x4* wp = (u32x4*)d_ws;
        int n = G_ * NC8 * NO;
        pack_weights_kernel<<<(n + 255) / 256, 256, 0, stream>>>(wraw, wp);
        wcorr_kernel<true><<<nblocks, 256, 0, stream>>>(in1, in2, wp, wraw, out);
    } else {
        wcorr_kernel<false><<<nblocks, 256, 0, stream>>>(in1, in2, nullptr, wraw, out);
    }
}